// Round 11
// baseline (211.828 us; speedup 1.0000x reference)
//
#include <hip/hip_runtime.h>
#include <hip/hip_bf16.h>

#define EMBED 1024
#define HEADS 16
#define HDIM 64
#define NB 4
#define SEQ 2048

typedef __bf16 bf16_t;
typedef bf16_t bf16x4 __attribute__((ext_vector_type(4)));
typedef bf16_t bf16x8 __attribute__((ext_vector_type(8)));
typedef float f32x4 __attribute__((ext_vector_type(4)));

static __device__ __forceinline__ bf16x8 cvt8(f32x4 a, f32x4 b) {
    bf16x8 r;
    r[0]=(bf16_t)a[0]; r[1]=(bf16_t)a[1]; r[2]=(bf16_t)a[2]; r[3]=(bf16_t)a[3];
    r[4]=(bf16_t)b[0]; r[5]=(bf16_t)b[1]; r[6]=(bf16_t)b[2]; r[7]=(bf16_t)b[3];
    return r;
}
static __device__ __forceinline__ bf16x8 load_cvt8(const float* __restrict__ p) {
    f32x4 a = *reinterpret_cast<const f32x4*>(p);
    f32x4 b = *reinterpret_cast<const f32x4*>(p + 4);
    return cvt8(a, b);
}
static __device__ __forceinline__ void gload_lds16(const bf16_t* g, bf16_t* l) {
    __builtin_amdgcn_global_load_lds((const __attribute__((address_space(1))) void*)g,
                                     (__attribute__((address_space(3))) void*)l, 16, 0, 0);
}

// ---------------- Wo -> bf16 pre-convert ----------------
__global__ __launch_bounds__(256) void wocvt_kernel(const float* __restrict__ Wo,
                                                    bf16_t* __restrict__ Wob) {
    const size_t i = ((size_t)blockIdx.x * 256 + threadIdx.x) * 8;
    f32x4 a = *reinterpret_cast<const f32x4*>(Wo + i);
    f32x4 b = *reinterpret_cast<const f32x4*>(Wo + i + 4);
    *(bf16x8*)(Wob + i) = cvt8(a, b);
}

// ---------------- Fused QKV projection ----------------
__global__ __launch_bounds__(256) void qkvproj_kernel(const float* __restrict__ Xq,
                                                      const float* __restrict__ Xk,
                                                      const float* __restrict__ Xv,
                                                      const float* __restrict__ Wq,
                                                      const float* __restrict__ Wk,
                                                      const float* __restrict__ Wv,
                                                      bf16_t* __restrict__ Qo,
                                                      bf16_t* __restrict__ Ko,
                                                      bf16_t* __restrict__ Vo,
                                                      float qscale) {
    const int mode = blockIdx.y;
    const float* X = (mode == 0) ? Xq : (mode == 1) ? Xk : Xv;
    const float* W = (mode == 0) ? Wq : (mode == 1) ? Wk : Wv;
    const int lane = threadIdx.x & 63, w = threadIdx.x >> 6;
    const int lr = lane & 15, g = lane >> 4;
    const int nh = blockIdx.x >> 5;
    const int sc = blockIdx.x & 31;
    const int n = nh >> 4, h = nh & 15;
    const int s0 = sc * 64 + w * 16;

    const float* xrow = X + ((size_t)n * SEQ + s0 + lr) * EMBED + h * HDIM;
    bf16x8 x0 = load_cvt8(xrow + g * 8);
    bf16x8 x1 = load_cvt8(xrow + 32 + g * 8);

    f32x4 acc[4] = {};
#pragma unroll
    for (int dt = 0; dt < 4; ++dt) {
        const float* wrow = W + (size_t)(dt * 16 + lr) * HDIM;
        bf16x8 w0 = load_cvt8(wrow + g * 8);
        bf16x8 w1 = load_cvt8(wrow + 32 + g * 8);
        if (mode == 2) {
            acc[dt] = __builtin_amdgcn_mfma_f32_16x16x32_bf16(x0, w0, acc[dt], 0, 0, 0);
            acc[dt] = __builtin_amdgcn_mfma_f32_16x16x32_bf16(x1, w1, acc[dt], 0, 0, 0);
        } else {
            acc[dt] = __builtin_amdgcn_mfma_f32_16x16x32_bf16(w0, x0, acc[dt], 0, 0, 0);
            acc[dt] = __builtin_amdgcn_mfma_f32_16x16x32_bf16(w1, x1, acc[dt], 0, 0, 0);
        }
    }
    if (mode == 2) {
#pragma unroll
        for (int et = 0; et < 4; ++et) {
            bf16x4 o;
#pragma unroll
            for (int r = 0; r < 4; ++r) o[r] = (bf16_t)acc[et][r];
            *(bf16x4*)(Vo + ((size_t)nh * HDIM + et * 16 + lr) * SEQ
                          + sc * 64 + ((w >> 1) << 5) + (g << 3) + ((w & 1) << 2)) = o;
        }
    } else {
        bf16_t* Yo = (mode == 0) ? Qo : Ko;
        const float scl = (mode == 0) ? qscale : 1.0f;
#pragma unroll
        for (int dt = 0; dt < 4; ++dt) {
            bf16x4 o;
#pragma unroll
            for (int r = 0; r < 4; ++r) o[r] = (bf16_t)(acc[dt][r] * scl);
            *(bf16x4*)(Yo + ((size_t)nh * SEQ + s0 + lr) * HDIM + dt * 16 + (g << 2)) = o;
        }
    }
}

// ------- Flash attention: barrier-free, K/V streamed from L2, QPW=64 -------
#define KT 64
#define QPW 64
#define QPB 256
#define NT (SEQ / KT)   // 32

__global__ __launch_bounds__(256, 2) void attn_kernel(const bf16_t* __restrict__ Qp,
                                                      const bf16_t* __restrict__ Kp,
                                                      const bf16_t* __restrict__ Vt_g,
                                                      const int* __restrict__ mask,
                                                      bf16_t* __restrict__ AO) {
    const int tid = threadIdx.x;
    const int lane = tid & 63;
    const int w = tid >> 6;          // 0..3 (waves fully independent; no barriers)
    const int lr = lane & 15, g = lane >> 4;

    const int nh = blockIdx.x & 63;  // XCD = bid%8 = nh%8: per-XCD K/V working set = 8*512KB = L2
    const int qb = blockIdx.x >> 6;  // 0..7
    const int n = nh >> 4, h = nh & 15;

    const bf16_t* Qh = Qp + (size_t)nh * SEQ * HDIM;
    const bf16_t* Kh = Kp + (size_t)nh * SEQ * HDIM;
    const bf16_t* Vh = Vt_g + (size_t)nh * HDIM * SEQ;   // [d][s_perm]
    const int* mrow = mask + n * SEQ;

    const int q0 = qb * QPB + w * QPW;
    bf16x8 Qreg[4][2];
#pragma unroll
    for (int qt = 0; qt < 4; ++qt)
#pragma unroll
        for (int hf = 0; hf < 2; ++hf)
            Qreg[qt][hf] = *(const bf16x8*)(Qh + (size_t)(q0 + qt * 16 + lr) * HDIM + hf * 32 + g * 8);

    // pack mask into one bit per tile (bit t = mask[t*64 + lane] != 0)
    unsigned int mbits = 0;
    for (int t = 0; t < NT; ++t)
        mbits |= (mrow[t * 64 + lane] != 0 ? 1u : 0u) << t;

    f32x4 accO[4][4] = {};
    f32x4 accL[4] = {};
    bf16x8 ones;
#pragma unroll
    for (int j = 0; j < 8; ++j) ones[j] = (bf16_t)1.0f;

    // lane-fixed base addresses (per-round increment is constant -> strength-reduced)
    const bf16_t* kbase0 = Kh + (size_t)lr * 64 + g * 8;        // + ct*16*64 + t*64*64
    const bf16_t* kbase1 = Kh + (size_t)lr * 64 + (4 + g) * 8;
    const bf16_t* vbase0 = Vh + (size_t)lr * SEQ + g * 8;       // + ctd*16*SEQ + t*64
    const bf16_t* vbase1 = Vh + (size_t)lr * SEQ + (4 + g) * 8;

    for (int t = 0; t < NT; ++t) {
        // issue all K then all V fragment loads for this tile (L2-resident; compiler
        // inserts counted vmcnt so QK starts when K lands, V lands under QK+softmax)
        bf16x8 kf[4][2], vf[4][2];
#pragma unroll
        for (int ct = 0; ct < 4; ++ct) {
            const size_t off = (size_t)(t * 64 + ct * 16) * 64;
            kf[ct][0] = *(const bf16x8*)(kbase0 + off);
            kf[ct][1] = *(const bf16x8*)(kbase1 + off);
        }
#pragma unroll
        for (int ctd = 0; ctd < 4; ++ctd) {
            const size_t off = (size_t)(ctd * 16) * SEQ + t * 64;
            vf[ctd][0] = *(const bf16x8*)(vbase0 + off);
            vf[ctd][1] = *(const bf16x8*)(vbase1 + off);
        }

        const int mbit = (int)((mbits >> t) & 1u);
        const bool allone = __all(mbit);

        // QK^T (A=K rows, B=Q) fused with exp2; P packed via v_cvt_pk_bf16_f32
        unsigned int pwl[4][4], pwh[4][4];
#pragma unroll
        for (int ct = 0; ct < 4; ++ct) {
#pragma unroll
            for (int qt = 0; qt < 4; ++qt) {
                f32x4 z = {};
                z = __builtin_amdgcn_mfma_f32_16x16x32_bf16(kf[ct][0], Qreg[qt][0], z, 0, 0, 0);
                z = __builtin_amdgcn_mfma_f32_16x16x32_bf16(kf[ct][1], Qreg[qt][1], z, 0, 0, 0);
                if (allone) {
#pragma unroll
                    for (int r = 0; r < 4; ++r) z[r] = __builtin_amdgcn_exp2f(z[r]);
                } else {
#pragma unroll
                    for (int r = 0; r < 4; ++r) {
                        int key = ct * 16 + g * 4 + r;
                        int mk = __shfl(mbit, key);
                        z[r] = mk ? __builtin_amdgcn_exp2f(z[r]) : 0.f;
                    }
                }
                unsigned int w0, w1;
                asm("v_cvt_pk_bf16_f32 %0, %1, %2" : "=v"(w0) : "v"(z[0]), "v"(z[1]));
                asm("v_cvt_pk_bf16_f32 %0, %1, %2" : "=v"(w1) : "v"(z[2]), "v"(z[3]));
                if (ct == 0)      { pwl[qt][0] = w0; pwl[qt][1] = w1; }
                else if (ct == 1) { pwl[qt][2] = w0; pwl[qt][3] = w1; }
                else if (ct == 2) { pwh[qt][0] = w0; pwh[qt][1] = w1; }
                else              { pwh[qt][2] = w0; pwh[qt][3] = w1; }
            }
        }

        // PV + denominator (ones-column MFMA; key-perm invariant)
        __builtin_amdgcn_s_setprio(1);
#pragma unroll
        for (int qt = 0; qt < 4; ++qt) {
            bf16x8 pa0 = *(const bf16x8*)&pwl[qt][0];
            bf16x8 pa1 = *(const bf16x8*)&pwh[qt][0];
            accL[qt] = __builtin_amdgcn_mfma_f32_16x16x32_bf16(pa0, ones, accL[qt], 0, 0, 0);
            accL[qt] = __builtin_amdgcn_mfma_f32_16x16x32_bf16(pa1, ones, accL[qt], 0, 0, 0);
        }
#pragma unroll
        for (int ctd = 0; ctd < 4; ++ctd) {
#pragma unroll
            for (int qt = 0; qt < 4; ++qt) {
                bf16x8 pa0 = *(const bf16x8*)&pwl[qt][0];
                bf16x8 pa1 = *(const bf16x8*)&pwh[qt][0];
                accO[qt][ctd] = __builtin_amdgcn_mfma_f32_16x16x32_bf16(pa0, vf[ctd][0], accO[qt][ctd], 0, 0, 0);
                accO[qt][ctd] = __builtin_amdgcn_mfma_f32_16x16x32_bf16(pa1, vf[ctd][1], accO[qt][ctd], 0, 0, 0);
            }
        }
        __builtin_amdgcn_s_setprio(0);
    }

    // epilogue: direct write
#pragma unroll
    for (int qt = 0; qt < 4; ++qt)
#pragma unroll
        for (int r = 0; r < 4; ++r) {
            float inv = 1.0f / accL[qt][r];
            int q = q0 + qt * 16 + g * 4 + r;
            bf16_t* orow = AO + ((size_t)(n * SEQ + q)) * EMBED + h * HDIM;
#pragma unroll
            for (int ctd = 0; ctd < 4; ++ctd)
                orow[ctd * 16 + lr] = (bf16_t)(accO[qt][ctd][r] * inv);
        }
}

// ------- Output projection: 128x128 tiles, DMA-staged bf16 A/B, XCD-local mapping -----
__global__ __launch_bounds__(256, 2) void outproj_kernel(const bf16_t* __restrict__ Xa,
                                                         const bf16_t* __restrict__ Wob,
                                                         const float* __restrict__ bo,
                                                         float* __restrict__ Out) {
    __shared__ __align__(16) bf16_t As[2][128 * 64];   // 16KB x2
    __shared__ __align__(16) bf16_t Bs[2][128 * 64];   // 16KB x2
    const int tid = threadIdx.x;
    const int lane = tid & 63, w = tid >> 6;
    const int lr = lane & 15, g = lane >> 4;
    const int wm = w >> 1, wn = w & 1;
    // XCD-local map: same-Xa-row blocks land on the same XCD (bid%8)
    const int bm = blockIdx.x & 63;   // 64 row-blocks
    const int bn = blockIdx.x >> 6;   // 8 col-blocks
    const int r0 = bm * 128, c0 = bn * 128;

    int srow[4], scx[4];
#pragma unroll
    for (int p = 0; p < 4; ++p) {
        srow[p] = p * 32 + w * 8 + (lane >> 3);
        scx[p] = (lane & 7) ^ (srow[p] & 7);    // pre-swizzled source chunk
    }

#define STG(s, b) { _Pragma("unroll") for (int p = 0; p < 4; ++p) { \
    gload_lds16(Xa  + (size_t)(r0 + srow[p]) * EMBED + (s) * 64 + scx[p] * 8, &As[b][0] + (p * 256 + w * 64) * 8); \
    gload_lds16(Wob + (size_t)(c0 + srow[p]) * EMBED + (s) * 64 + scx[p] * 8, &Bs[b][0] + (p * 256 + w * 64) * 8); } }

    f32x4 acc[4][4] = {};

    STG(0, 0);

    for (int ks = 0; ks < 16; ++ks) {
        const int cur = ks & 1;
        asm volatile("s_waitcnt vmcnt(0)" ::: "memory");
        __builtin_amdgcn_s_barrier();
        __builtin_amdgcn_sched_barrier(0);
        if (ks + 1 < 16) STG(ks + 1, cur ^ 1);

        const bf16_t* Ab = As[cur];
        const bf16_t* Bb = Bs[cur];
#pragma unroll
        for (int hf = 0; hf < 2; ++hf) {
            bf16x8 af[4], bfr[4];
#pragma unroll
            for (int i = 0; i < 4; ++i) {
                int ar = wm * 64 + i * 16 + lr;
                af[i] = *(const bf16x8*)(Ab + ar * 64 + (((hf * 4 + g) ^ (ar & 7)) << 3));
                int br = wn * 64 + i * 16 + lr;
                bfr[i] = *(const bf16x8*)(Bb + br * 64 + (((hf * 4 + g) ^ (br & 7)) << 3));
            }
            __builtin_amdgcn_s_setprio(1);
#pragma unroll
            for (int i = 0; i < 4; ++i)
#pragma unroll
                for (int j = 0; j < 4; ++j)
                    acc[i][j] = __builtin_amdgcn_mfma_f32_16x16x32_bf16(af[i], bfr[j], acc[i][j], 0, 0, 0);
            __builtin_amdgcn_s_setprio(0);
        }
    }
#undef STG

#pragma unroll
    for (int i = 0; i < 4; ++i)
#pragma unroll
        for (int r = 0; r < 4; ++r) {
            int row = r0 + wm * 64 + i * 16 + g * 4 + r;
            float* orow = Out + (size_t)row * EMBED;
#pragma unroll
            for (int j = 0; j < 4; ++j) {
                int col = c0 + wn * 64 + j * 16 + lr;
                orow[col] = acc[i][j][r] + bo[col];
            }
        }
}

extern "C" void kernel_launch(void* const* d_in, const int* in_sizes, int n_in,
                              void* d_out, int out_size, void* d_ws, size_t ws_size,
                              hipStream_t stream) {
    const float* values = (const float*)d_in[0];
    const float* keys   = (const float*)d_in[1];
    const float* query  = (const float*)d_in[2];
    const int*   mask   = (const int*)d_in[3];
    const float* Wv = (const float*)d_in[4];
    const float* Wk = (const float*)d_in[5];
    const float* Wq = (const float*)d_in[6];
    const float* Wo = (const float*)d_in[7];
    const float* bo = (const float*)d_in[8];
    float* out = (float*)d_out;

    char* ws = (char*)d_ws;
    const size_t SZ = (size_t)NB * HEADS * SEQ * HDIM * sizeof(bf16_t);  // 16 MB
    bf16_t* Qp  = (bf16_t*)(ws);
    bf16_t* Kp  = (bf16_t*)(ws + SZ);
    bf16_t* Vt  = (bf16_t*)(ws + 2 * SZ);
    bf16_t* Xa  = (bf16_t*)(ws + 3 * SZ);
    bf16_t* Wob = (bf16_t*)(ws + 4 * SZ);   // 2 MB

    const float qscale = 0.0450842200278f;  // log2(e) / sqrt(1024)

    dim3 blk(256);
    wocvt_kernel<<<dim3((EMBED * EMBED) / (256 * 8)), blk, 0, stream>>>(Wo, Wob);

    dim3 gproj(2048, 3);
    qkvproj_kernel<<<gproj, blk, 0, stream>>>(query, keys, values, Wq, Wk, Wv,
                                              Qp, Kp, Vt, qscale);

    const int attn_grid = 64 * (SEQ / QPB);   // 512
    attn_kernel<<<dim3(attn_grid), blk, 0, stream>>>(Qp, Kp, Vt, mask, Xa);

    outproj_kernel<<<dim3(512), blk, 0, stream>>>(Xa, Wob, bo, out);
}

// Round 12
// 146.951 us; speedup vs baseline: 1.4415x; 1.4415x over previous
//
#include <hip/hip_runtime.h>
#include <hip/hip_bf16.h>

#define EMBED 1024
#define HEADS 16
#define HDIM 64
#define NB 4
#define SEQ 2048

typedef __bf16 bf16_t;
typedef bf16_t bf16x4 __attribute__((ext_vector_type(4)));
typedef bf16_t bf16x8 __attribute__((ext_vector_type(8)));
typedef float f32x4 __attribute__((ext_vector_type(4)));

static __device__ __forceinline__ bf16x8 cvt8(f32x4 a, f32x4 b) {
    bf16x8 r;
    r[0]=(bf16_t)a[0]; r[1]=(bf16_t)a[1]; r[2]=(bf16_t)a[2]; r[3]=(bf16_t)a[3];
    r[4]=(bf16_t)b[0]; r[5]=(bf16_t)b[1]; r[6]=(bf16_t)b[2]; r[7]=(bf16_t)b[3];
    return r;
}
static __device__ __forceinline__ bf16x8 load_cvt8(const float* __restrict__ p) {
    f32x4 a = *reinterpret_cast<const f32x4*>(p);
    f32x4 b = *reinterpret_cast<const f32x4*>(p + 4);
    return cvt8(a, b);
}
static __device__ __forceinline__ void gload_lds16(const bf16_t* g, bf16_t* l) {
    __builtin_amdgcn_global_load_lds((const __attribute__((address_space(1))) void*)g,
                                     (__attribute__((address_space(3))) void*)l, 16, 0, 0);
}

// ---------------- Wo -> bf16 pre-convert ----------------
__global__ __launch_bounds__(256) void wocvt_kernel(const float* __restrict__ Wo,
                                                    bf16_t* __restrict__ Wob) {
    const size_t i = ((size_t)blockIdx.x * 256 + threadIdx.x) * 8;
    f32x4 a = *reinterpret_cast<const f32x4*>(Wo + i);
    f32x4 b = *reinterpret_cast<const f32x4*>(Wo + i + 4);
    *(bf16x8*)(Wob + i) = cvt8(a, b);
}

// ---------------- Fused QKV projection: 256 s-rows/block, W in registers ----------------
__global__ __launch_bounds__(256) void qkvproj_kernel(const float* __restrict__ Xq,
                                                      const float* __restrict__ Xk,
                                                      const float* __restrict__ Xv,
                                                      const float* __restrict__ Wq,
                                                      const float* __restrict__ Wk,
                                                      const float* __restrict__ Wv,
                                                      bf16_t* __restrict__ Qo,
                                                      bf16_t* __restrict__ Ko,
                                                      bf16_t* __restrict__ Vo,
                                                      float qscale) {
    const int mode = blockIdx.y;
    const float* X = (mode == 0) ? Xq : (mode == 1) ? Xk : Xv;
    const float* W = (mode == 0) ? Wq : (mode == 1) ? Wk : Wv;
    const int lane = threadIdx.x & 63, w = threadIdx.x >> 6;
    const int lr = lane & 15, g = lane >> 4;
    const int nh = blockIdx.x >> 3;    // 64
    const int scb = blockIdx.x & 7;    // 8 super-chunks of 256 s
    const int n = nh >> 4, h = nh & 15;

    // W fragments once per block (same regs serve A- and B-operand roles)
    bf16x8 wA[4][2];
#pragma unroll
    for (int dt = 0; dt < 4; ++dt) {
        const float* wrow = W + (size_t)(dt * 16 + lr) * HDIM;
        wA[dt][0] = load_cvt8(wrow + g * 8);
        wA[dt][1] = load_cvt8(wrow + 32 + g * 8);
    }

#pragma unroll
    for (int it = 0; it < 4; ++it) {
        const int s0 = scb * 256 + it * 64 + w * 16;
        const float* xrow = X + ((size_t)n * SEQ + s0 + lr) * EMBED + h * HDIM;
        bf16x8 x0 = load_cvt8(xrow + g * 8);
        bf16x8 x1 = load_cvt8(xrow + 32 + g * 8);

        f32x4 acc[4] = {};
#pragma unroll
        for (int dt = 0; dt < 4; ++dt) {
            if (mode == 2) {
                acc[dt] = __builtin_amdgcn_mfma_f32_16x16x32_bf16(x0, wA[dt][0], acc[dt], 0, 0, 0);
                acc[dt] = __builtin_amdgcn_mfma_f32_16x16x32_bf16(x1, wA[dt][1], acc[dt], 0, 0, 0);
            } else {
                acc[dt] = __builtin_amdgcn_mfma_f32_16x16x32_bf16(wA[dt][0], x0, acc[dt], 0, 0, 0);
                acc[dt] = __builtin_amdgcn_mfma_f32_16x16x32_bf16(wA[dt][1], x1, acc[dt], 0, 0, 0);
            }
        }
        if (mode == 2) {
            const int sc4 = scb * 4 + it;
#pragma unroll
            for (int et = 0; et < 4; ++et) {
                bf16x4 o;
#pragma unroll
                for (int r = 0; r < 4; ++r) o[r] = (bf16_t)acc[et][r];
                *(bf16x4*)(Vo + ((size_t)nh * HDIM + et * 16 + lr) * SEQ
                              + sc4 * 64 + ((w >> 1) << 5) + (g << 3) + ((w & 1) << 2)) = o;
            }
        } else {
            bf16_t* Yo = (mode == 0) ? Qo : Ko;
            const float scl = (mode == 0) ? qscale : 1.0f;
#pragma unroll
            for (int dt = 0; dt < 4; ++dt) {
                bf16x4 o;
#pragma unroll
                for (int r = 0; r < 4; ++r) o[r] = (bf16_t)(acc[dt][r] * scl);
                *(bf16x4*)(Yo + ((size_t)nh * SEQ + s0 + lr) * HDIM + dt * 16 + (g << 2)) = o;
            }
        }
    }
}

// ------- Flash attention: 4-wave blocks, QPW=32, dbuf DMA staging (R9 structure) -------
#define KT 64
#define QPW 32
#define QPB 128
#define NT (SEQ / KT)   // 32

__global__ __launch_bounds__(256, 4) void attn_kernel(const bf16_t* __restrict__ Qp,
                                                      const bf16_t* __restrict__ Kp,
                                                      const bf16_t* __restrict__ Vt_g,
                                                      const int* __restrict__ mask,
                                                      bf16_t* __restrict__ AO) {
    __shared__ __align__(16) bf16_t Kt[2][64 * 64];   // 16KB
    __shared__ __align__(16) bf16_t Vt[2][64 * 64];   // 16KB

    const int tid = threadIdx.x;
    const int lane = tid & 63;
    const int w = tid >> 6;          // 0..3
    const int lr = lane & 15, g = lane >> 4;

    const int nh = blockIdx.x & 63;  // XCD locality
    const int qb = blockIdx.x >> 6;  // 0..15
    const int n = nh >> 4, h = nh & 15;

    const bf16_t* Qh = Qp + (size_t)nh * SEQ * HDIM;
    const bf16_t* Kh = Kp + (size_t)nh * SEQ * HDIM;
    const bf16_t* Vh = Vt_g + (size_t)nh * HDIM * SEQ;   // [d][s_perm]
    const int* mrow = mask + n * SEQ;

    const int q0 = qb * QPB + w * QPW;
    bf16x8 Qreg[2][2];
#pragma unroll
    for (int qt = 0; qt < 2; ++qt)
#pragma unroll
        for (int hf = 0; hf < 2; ++hf)
            Qreg[qt][hf] = *(const bf16x8*)(Qh + (size_t)(q0 + qt * 16 + lr) * HDIM + hf * 32 + g * 8);

    // pack mask into one bit per tile (bit t = mask[t*64 + lane] != 0)
    unsigned int mbits = 0;
    for (int t = 0; t < NT; ++t)
        mbits |= (mrow[t * 64 + lane] != 0 ? 1u : 0u) << t;

    // staging geometry: thread covers rows srow, srow+32 of each 64x64 tile
    const int srow = (w << 3) + (lane >> 3);        // 0..31
    const int sx = (lane & 7) ^ (srow & 7);         // pre-swizzled chunk (same for srow+32)

#define STAGE(t, b) { \
    gload_lds16(Kh + ((size_t)((t) * 64 + srow)) * 64 + sx * 8,      &Kt[b][0]    + w * 512); \
    gload_lds16(Kh + ((size_t)((t) * 64 + srow + 32)) * 64 + sx * 8, &Kt[b][2048] + w * 512); \
    gload_lds16(Vh + (size_t)srow * SEQ + (t) * 64 + sx * 8,         &Vt[b][0]    + w * 512); \
    gload_lds16(Vh + (size_t)(srow + 32) * SEQ + (t) * 64 + sx * 8,  &Vt[b][2048] + w * 512); }

    f32x4 accO[2][4] = {};
    f32x4 accL[2] = {};
    bf16x8 ones;
#pragma unroll
    for (int j = 0; j < 8; ++j) ones[j] = (bf16_t)1.0f;

    STAGE(0, 0);

    for (int t = 0; t < NT; ++t) {
        const int cur = t & 1;
        asm volatile("s_waitcnt vmcnt(0)" ::: "memory");
        __builtin_amdgcn_s_barrier();
        __builtin_amdgcn_sched_barrier(0);
        if (t + 1 < NT) STAGE(t + 1, cur ^ 1);

        const bf16_t* Kb = &Kt[cur][0];
        const bf16_t* Vb = &Vt[cur][0];

        const int mbit = (int)((mbits >> t) & 1u);
        const bool allone = __all(mbit);

        // QK^T (A=K rows, B=Q) fused with exp2; P packed via v_cvt_pk_bf16_f32
        unsigned int pwl[2][4], pwh[2][4];
#pragma unroll
        for (int ct = 0; ct < 4; ++ct) {
            int row = ct * 16 + lr, rs = row & 7;
            bf16x8 kf0 = *(const bf16x8*)(Kb + row * 64 + ((g ^ rs) << 3));
            bf16x8 kf1 = *(const bf16x8*)(Kb + row * 64 + (((4 + g) ^ rs) << 3));
#pragma unroll
            for (int qt = 0; qt < 2; ++qt) {
                f32x4 z = {};
                z = __builtin_amdgcn_mfma_f32_16x16x32_bf16(kf0, Qreg[qt][0], z, 0, 0, 0);
                z = __builtin_amdgcn_mfma_f32_16x16x32_bf16(kf1, Qreg[qt][1], z, 0, 0, 0);
                if (allone) {
#pragma unroll
                    for (int r = 0; r < 4; ++r) z[r] = __builtin_amdgcn_exp2f(z[r]);
                } else {
#pragma unroll
                    for (int r = 0; r < 4; ++r) {
                        int key = ct * 16 + g * 4 + r;
                        int mk = __shfl(mbit, key);
                        z[r] = mk ? __builtin_amdgcn_exp2f(z[r]) : 0.f;
                    }
                }
                unsigned int w0, w1;
                asm("v_cvt_pk_bf16_f32 %0, %1, %2" : "=v"(w0) : "v"(z[0]), "v"(z[1]));
                asm("v_cvt_pk_bf16_f32 %0, %1, %2" : "=v"(w1) : "v"(z[2]), "v"(z[3]));
                if (ct == 0)      { pwl[qt][0] = w0; pwl[qt][1] = w1; }
                else if (ct == 1) { pwl[qt][2] = w0; pwl[qt][3] = w1; }
                else if (ct == 2) { pwh[qt][0] = w0; pwh[qt][1] = w1; }
                else              { pwh[qt][2] = w0; pwh[qt][3] = w1; }
            }
        }

        // PV + denominator (ones-column MFMA; key-perm invariant)
        __builtin_amdgcn_s_setprio(1);
#pragma unroll
        for (int qt = 0; qt < 2; ++qt) {
            bf16x8 pa0 = *(const bf16x8*)&pwl[qt][0];
            bf16x8 pa1 = *(const bf16x8*)&pwh[qt][0];
            accL[qt] = __builtin_amdgcn_mfma_f32_16x16x32_bf16(pa0, ones, accL[qt], 0, 0, 0);
            accL[qt] = __builtin_amdgcn_mfma_f32_16x16x32_bf16(pa1, ones, accL[qt], 0, 0, 0);
        }
#pragma unroll
        for (int ctd = 0; ctd < 4; ++ctd) {
            int row = ctd * 16 + lr, rs = row & 7;
            bf16x8 vf0 = *(const bf16x8*)(Vb + row * 64 + ((g ^ rs) << 3));
            bf16x8 vf1 = *(const bf16x8*)(Vb + row * 64 + (((4 + g) ^ rs) << 3));
#pragma unroll
            for (int qt = 0; qt < 2; ++qt) {
                bf16x8 pa0 = *(const bf16x8*)&pwl[qt][0];
                bf16x8 pa1 = *(const bf16x8*)&pwh[qt][0];
                accO[qt][ctd] = __builtin_amdgcn_mfma_f32_16x16x32_bf16(pa0, vf0, accO[qt][ctd], 0, 0, 0);
                accO[qt][ctd] = __builtin_amdgcn_mfma_f32_16x16x32_bf16(pa1, vf1, accO[qt][ctd], 0, 0, 0);
            }
        }
        __builtin_amdgcn_s_setprio(0);
    }
#undef STAGE

    // epilogue: direct write
#pragma unroll
    for (int qt = 0; qt < 2; ++qt)
#pragma unroll
        for (int r = 0; r < 4; ++r) {
            float inv = 1.0f / accL[qt][r];
            int q = q0 + qt * 16 + g * 4 + r;
            bf16_t* orow = AO + ((size_t)(n * SEQ + q)) * EMBED + h * HDIM;
#pragma unroll
            for (int ctd = 0; ctd < 4; ++ctd)
                orow[ctd * 16 + lr] = (bf16_t)(accO[qt][ctd][r] * inv);
        }
}

// ------- Output projection: 128x128 tiles, DMA-staged bf16 A/B, XCD-local mapping -----
__global__ __launch_bounds__(256, 2) void outproj_kernel(const bf16_t* __restrict__ Xa,
                                                         const bf16_t* __restrict__ Wob,
                                                         const float* __restrict__ bo,
                                                         float* __restrict__ Out) {
    __shared__ __align__(16) bf16_t As[2][128 * 64];   // 16KB x2
    __shared__ __align__(16) bf16_t Bs[2][128 * 64];   // 16KB x2
    const int tid = threadIdx.x;
    const int lane = tid & 63, w = tid >> 6;
    const int lr = lane & 15, g = lane >> 4;
    const int wm = w >> 1, wn = w & 1;
    // XCD-local map: same-Xa-row blocks land on the same XCD (bid%8)
    const int bm = blockIdx.x & 63;   // 64 row-blocks
    const int bn = blockIdx.x >> 6;   // 8 col-blocks
    const int r0 = bm * 128, c0 = bn * 128;

    int srow[4], scx[4];
#pragma unroll
    for (int p = 0; p < 4; ++p) {
        srow[p] = p * 32 + w * 8 + (lane >> 3);
        scx[p] = (lane & 7) ^ (srow[p] & 7);    // pre-swizzled source chunk
    }

#define STG(s, b) { _Pragma("unroll") for (int p = 0; p < 4; ++p) { \
    gload_lds16(Xa  + (size_t)(r0 + srow[p]) * EMBED + (s) * 64 + scx[p] * 8, &As[b][0] + (p * 256 + w * 64) * 8); \
    gload_lds16(Wob + (size_t)(c0 + srow[p]) * EMBED + (s) * 64 + scx[p] * 8, &Bs[b][0] + (p * 256 + w * 64) * 8); } }

    f32x4 acc[4][4] = {};

    STG(0, 0);

    for (int ks = 0; ks < 16; ++ks) {
        const int cur = ks & 1;
        asm volatile("s_waitcnt vmcnt(0)" ::: "memory");
        __builtin_amdgcn_s_barrier();
        __builtin_amdgcn_sched_barrier(0);
        if (ks + 1 < 16) STG(ks + 1, cur ^ 1);

        const bf16_t* Ab = As[cur];
        const bf16_t* Bb = Bs[cur];
#pragma unroll
        for (int hf = 0; hf < 2; ++hf) {
            bf16x8 af[4], bfr[4];
#pragma unroll
            for (int i = 0; i < 4; ++i) {
                int ar = wm * 64 + i * 16 + lr;
                af[i] = *(const bf16x8*)(Ab + ar * 64 + (((hf * 4 + g) ^ (ar & 7)) << 3));
                int br = wn * 64 + i * 16 + lr;
                bfr[i] = *(const bf16x8*)(Bb + br * 64 + (((hf * 4 + g) ^ (br & 7)) << 3));
            }
            __builtin_amdgcn_s_setprio(1);
#pragma unroll
            for (int i = 0; i < 4; ++i)
#pragma unroll
                for (int j = 0; j < 4; ++j)
                    acc[i][j] = __builtin_amdgcn_mfma_f32_16x16x32_bf16(af[i], bfr[j], acc[i][j], 0, 0, 0);
            __builtin_amdgcn_s_setprio(0);
        }
    }
#undef STG

#pragma unroll
    for (int i = 0; i < 4; ++i)
#pragma unroll
        for (int r = 0; r < 4; ++r) {
            int row = r0 + wm * 64 + i * 16 + g * 4 + r;
            float* orow = Out + (size_t)row * EMBED;
#pragma unroll
            for (int j = 0; j < 4; ++j) {
                int col = c0 + wn * 64 + j * 16 + lr;
                orow[col] = acc[i][j][r] + bo[col];
            }
        }
}

extern "C" void kernel_launch(void* const* d_in, const int* in_sizes, int n_in,
                              void* d_out, int out_size, void* d_ws, size_t ws_size,
                              hipStream_t stream) {
    const float* values = (const float*)d_in[0];
    const float* keys   = (const float*)d_in[1];
    const float* query  = (const float*)d_in[2];
    const int*   mask   = (const int*)d_in[3];
    const float* Wv = (const float*)d_in[4];
    const float* Wk = (const float*)d_in[5];
    const float* Wq = (const float*)d_in[6];
    const float* Wo = (const float*)d_in[7];
    const float* bo = (const float*)d_in[8];
    float* out = (float*)d_out;

    char* ws = (char*)d_ws;
    const size_t SZ = (size_t)NB * HEADS * SEQ * HDIM * sizeof(bf16_t);  // 16 MB
    bf16_t* Qp  = (bf16_t*)(ws);
    bf16_t* Kp  = (bf16_t*)(ws + SZ);
    bf16_t* Vt  = (bf16_t*)(ws + 2 * SZ);
    bf16_t* Xa  = (bf16_t*)(ws + 3 * SZ);
    bf16_t* Wob = (bf16_t*)(ws + 4 * SZ);   // 2 MB

    const float qscale = 0.0450842200278f;  // log2(e) / sqrt(1024)

    dim3 blk(256);
    wocvt_kernel<<<dim3((EMBED * EMBED) / (256 * 8)), blk, 0, stream>>>(Wo, Wob);

    dim3 gproj(512, 3);
    qkvproj_kernel<<<gproj, blk, 0, stream>>>(query, keys, values, Wq, Wk, Wv,
                                              Qp, Kp, Vt, qscale);

    const int attn_grid = 64 * (SEQ / QPB);   // 1024
    attn_kernel<<<dim3(attn_grid), blk, 0, stream>>>(Qp, Kp, Vt, mask, Xa);

    outproj_kernel<<<dim3(512), blk, 0, stream>>>(Xa, Wob, bo, out);
}

// Round 13
// 141.125 us; speedup vs baseline: 1.5010x; 1.0413x over previous
//
#include <hip/hip_runtime.h>
#include <hip/hip_bf16.h>

#define EMBED 1024
#define HEADS 16
#define HDIM 64
#define NB 4
#define SEQ 2048

typedef __bf16 bf16_t;
typedef bf16_t bf16x4 __attribute__((ext_vector_type(4)));
typedef bf16_t bf16x8 __attribute__((ext_vector_type(8)));
typedef float f32x4 __attribute__((ext_vector_type(4)));

static __device__ __forceinline__ bf16x8 cvt8(f32x4 a, f32x4 b) {
    bf16x8 r;
    r[0]=(bf16_t)a[0]; r[1]=(bf16_t)a[1]; r[2]=(bf16_t)a[2]; r[3]=(bf16_t)a[3];
    r[4]=(bf16_t)b[0]; r[5]=(bf16_t)b[1]; r[6]=(bf16_t)b[2]; r[7]=(bf16_t)b[3];
    return r;
}
static __device__ __forceinline__ bf16x8 load_cvt8(const float* __restrict__ p) {
    f32x4 a = *reinterpret_cast<const f32x4*>(p);
    f32x4 b = *reinterpret_cast<const f32x4*>(p + 4);
    return cvt8(a, b);
}
static __device__ __forceinline__ void gload_lds16(const bf16_t* g, bf16_t* l) {
    __builtin_amdgcn_global_load_lds((const __attribute__((address_space(1))) void*)g,
                                     (__attribute__((address_space(3))) void*)l, 16, 0, 0);
}

// ------- Fused QKV projection + Wo convert (mode 3) -------
__global__ __launch_bounds__(256) void qkvproj_kernel(const float* __restrict__ Xq,
                                                      const float* __restrict__ Xk,
                                                      const float* __restrict__ Xv,
                                                      const float* __restrict__ Wq,
                                                      const float* __restrict__ Wk,
                                                      const float* __restrict__ Wv,
                                                      const float* __restrict__ Wo,
                                                      bf16_t* __restrict__ Qo,
                                                      bf16_t* __restrict__ Ko,
                                                      bf16_t* __restrict__ Vo,
                                                      bf16_t* __restrict__ Wob,
                                                      float qscale) {
    const int mode = blockIdx.y;
    if (mode == 3) {   // Wo -> bf16
        const size_t i = ((size_t)blockIdx.x * 256 + threadIdx.x) * 8;
        f32x4 a = *reinterpret_cast<const f32x4*>(Wo + i);
        f32x4 b = *reinterpret_cast<const f32x4*>(Wo + i + 4);
        *(bf16x8*)(Wob + i) = cvt8(a, b);
        return;
    }
    const float* X = (mode == 0) ? Xq : (mode == 1) ? Xk : Xv;
    const float* W = (mode == 0) ? Wq : (mode == 1) ? Wk : Wv;
    const int lane = threadIdx.x & 63, w = threadIdx.x >> 6;
    const int lr = lane & 15, g = lane >> 4;
    const int nh = blockIdx.x >> 3;    // 64
    const int scb = blockIdx.x & 7;    // 8 super-chunks of 256 s
    const int n = nh >> 4, h = nh & 15;

    // W fragments once per block
    bf16x8 wA[4][2];
#pragma unroll
    for (int dt = 0; dt < 4; ++dt) {
        const float* wrow = W + (size_t)(dt * 16 + lr) * HDIM;
        wA[dt][0] = load_cvt8(wrow + g * 8);
        wA[dt][1] = load_cvt8(wrow + 32 + g * 8);
    }

#pragma unroll
    for (int it = 0; it < 4; ++it) {
        const int s0 = scb * 256 + it * 64 + w * 16;
        const float* xrow = X + ((size_t)n * SEQ + s0 + lr) * EMBED + h * HDIM;
        bf16x8 x0 = load_cvt8(xrow + g * 8);
        bf16x8 x1 = load_cvt8(xrow + 32 + g * 8);

        f32x4 acc[4] = {};
#pragma unroll
        for (int dt = 0; dt < 4; ++dt) {
            if (mode == 2) {
                acc[dt] = __builtin_amdgcn_mfma_f32_16x16x32_bf16(x0, wA[dt][0], acc[dt], 0, 0, 0);
                acc[dt] = __builtin_amdgcn_mfma_f32_16x16x32_bf16(x1, wA[dt][1], acc[dt], 0, 0, 0);
            } else {
                acc[dt] = __builtin_amdgcn_mfma_f32_16x16x32_bf16(wA[dt][0], x0, acc[dt], 0, 0, 0);
                acc[dt] = __builtin_amdgcn_mfma_f32_16x16x32_bf16(wA[dt][1], x1, acc[dt], 0, 0, 0);
            }
        }
        if (mode == 2) {
            const int sc4 = scb * 4 + it;
#pragma unroll
            for (int et = 0; et < 4; ++et) {
                bf16x4 o;
#pragma unroll
                for (int r = 0; r < 4; ++r) o[r] = (bf16_t)acc[et][r];
                *(bf16x4*)(Vo + ((size_t)nh * HDIM + et * 16 + lr) * SEQ
                              + sc4 * 64 + ((w >> 1) << 5) + (g << 3) + ((w & 1) << 2)) = o;
            }
        } else {
            bf16_t* Yo = (mode == 0) ? Qo : Ko;
            const float scl = (mode == 0) ? qscale : 1.0f;
#pragma unroll
            for (int dt = 0; dt < 4; ++dt) {
                bf16x4 o;
#pragma unroll
                for (int r = 0; r < 4; ++r) o[r] = (bf16_t)(acc[dt][r] * scl);
                *(bf16x4*)(Yo + ((size_t)nh * SEQ + s0 + lr) * HDIM + dt * 16 + (g << 2)) = o;
            }
        }
    }
}

// ------- Flash attention: 4-wave blocks, QPW=32, dbuf DMA staging (R9 structure) -------
#define KT 64
#define QPW 32
#define QPB 128
#define NT (SEQ / KT)   // 32

__global__ __launch_bounds__(256, 4) void attn_kernel(const bf16_t* __restrict__ Qp,
                                                      const bf16_t* __restrict__ Kp,
                                                      const bf16_t* __restrict__ Vt_g,
                                                      const int* __restrict__ mask,
                                                      bf16_t* __restrict__ AO) {
    __shared__ __align__(16) bf16_t Kt[2][64 * 64];   // 16KB
    __shared__ __align__(16) bf16_t Vt[2][64 * 64];   // 16KB

    const int tid = threadIdx.x;
    const int lane = tid & 63;
    const int w = tid >> 6;          // 0..3
    const int lr = lane & 15, g = lane >> 4;

    const int nh = blockIdx.x & 63;  // XCD locality
    const int qb = blockIdx.x >> 6;  // 0..15
    const int n = nh >> 4, h = nh & 15;

    const bf16_t* Qh = Qp + (size_t)nh * SEQ * HDIM;
    const bf16_t* Kh = Kp + (size_t)nh * SEQ * HDIM;
    const bf16_t* Vh = Vt_g + (size_t)nh * HDIM * SEQ;   // [d][s_perm]
    const int* mrow = mask + n * SEQ;

    const int q0 = qb * QPB + w * QPW;
    bf16x8 Qreg[2][2];
#pragma unroll
    for (int qt = 0; qt < 2; ++qt)
#pragma unroll
        for (int hf = 0; hf < 2; ++hf)
            Qreg[qt][hf] = *(const bf16x8*)(Qh + (size_t)(q0 + qt * 16 + lr) * HDIM + hf * 32 + g * 8);

    // pack mask into one bit per tile (bit t = mask[t*64 + lane] != 0)
    unsigned int mbits = 0;
    for (int t = 0; t < NT; ++t)
        mbits |= (mrow[t * 64 + lane] != 0 ? 1u : 0u) << t;

    // staging geometry: thread covers rows srow, srow+32 of each 64x64 tile
    const int srow = (w << 3) + (lane >> 3);        // 0..31
    const int sx = (lane & 7) ^ (srow & 7);         // pre-swizzled chunk (same for srow+32)

#define STAGE(t, b) { \
    gload_lds16(Kh + ((size_t)((t) * 64 + srow)) * 64 + sx * 8,      &Kt[b][0]    + w * 512); \
    gload_lds16(Kh + ((size_t)((t) * 64 + srow + 32)) * 64 + sx * 8, &Kt[b][2048] + w * 512); \
    gload_lds16(Vh + (size_t)srow * SEQ + (t) * 64 + sx * 8,         &Vt[b][0]    + w * 512); \
    gload_lds16(Vh + (size_t)(srow + 32) * SEQ + (t) * 64 + sx * 8,  &Vt[b][2048] + w * 512); }

    f32x4 accO[2][4] = {};
    f32x4 accL[2] = {};
    bf16x8 ones;
#pragma unroll
    for (int j = 0; j < 8; ++j) ones[j] = (bf16_t)1.0f;

    STAGE(0, 0);

    for (int t = 0; t < NT; ++t) {
        const int cur = t & 1;
        asm volatile("s_waitcnt vmcnt(0)" ::: "memory");
        __builtin_amdgcn_s_barrier();
        __builtin_amdgcn_sched_barrier(0);
        if (t + 1 < NT) STAGE(t + 1, cur ^ 1);

        const bf16_t* Kb = &Kt[cur][0];
        const bf16_t* Vb = &Vt[cur][0];

        const int mbit = (int)((mbits >> t) & 1u);
        const bool allone = __all(mbit);

        // QK^T (A=K rows, B=Q) fused with exp2; P packed via v_cvt_pk_bf16_f32
        unsigned int pwl[2][4], pwh[2][4];
#pragma unroll
        for (int ct = 0; ct < 4; ++ct) {
            int row = ct * 16 + lr, rs = row & 7;
            bf16x8 kf0 = *(const bf16x8*)(Kb + row * 64 + ((g ^ rs) << 3));
            bf16x8 kf1 = *(const bf16x8*)(Kb + row * 64 + (((4 + g) ^ rs) << 3));
#pragma unroll
            for (int qt = 0; qt < 2; ++qt) {
                f32x4 z = {};
                z = __builtin_amdgcn_mfma_f32_16x16x32_bf16(kf0, Qreg[qt][0], z, 0, 0, 0);
                z = __builtin_amdgcn_mfma_f32_16x16x32_bf16(kf1, Qreg[qt][1], z, 0, 0, 0);
                if (allone) {
#pragma unroll
                    for (int r = 0; r < 4; ++r) z[r] = __builtin_amdgcn_exp2f(z[r]);
                } else {
#pragma unroll
                    for (int r = 0; r < 4; ++r) {
                        int key = ct * 16 + g * 4 + r;
                        int mk = __shfl(mbit, key);
                        z[r] = mk ? __builtin_amdgcn_exp2f(z[r]) : 0.f;
                    }
                }
                unsigned int w0, w1;
                asm("v_cvt_pk_bf16_f32 %0, %1, %2" : "=v"(w0) : "v"(z[0]), "v"(z[1]));
                asm("v_cvt_pk_bf16_f32 %0, %1, %2" : "=v"(w1) : "v"(z[2]), "v"(z[3]));
                if (ct == 0)      { pwl[qt][0] = w0; pwl[qt][1] = w1; }
                else if (ct == 1) { pwl[qt][2] = w0; pwl[qt][3] = w1; }
                else if (ct == 2) { pwh[qt][0] = w0; pwh[qt][1] = w1; }
                else              { pwh[qt][2] = w0; pwh[qt][3] = w1; }
            }
        }

        // PV + denominator (ones-column MFMA; key-perm invariant)
        __builtin_amdgcn_s_setprio(1);
#pragma unroll
        for (int qt = 0; qt < 2; ++qt) {
            bf16x8 pa0 = *(const bf16x8*)&pwl[qt][0];
            bf16x8 pa1 = *(const bf16x8*)&pwh[qt][0];
            accL[qt] = __builtin_amdgcn_mfma_f32_16x16x32_bf16(pa0, ones, accL[qt], 0, 0, 0);
            accL[qt] = __builtin_amdgcn_mfma_f32_16x16x32_bf16(pa1, ones, accL[qt], 0, 0, 0);
        }
#pragma unroll
        for (int ctd = 0; ctd < 4; ++ctd) {
            int row = ctd * 16 + lr, rs = row & 7;
            bf16x8 vf0 = *(const bf16x8*)(Vb + row * 64 + ((g ^ rs) << 3));
            bf16x8 vf1 = *(const bf16x8*)(Vb + row * 64 + (((4 + g) ^ rs) << 3));
#pragma unroll
            for (int qt = 0; qt < 2; ++qt) {
                bf16x8 pa0 = *(const bf16x8*)&pwl[qt][0];
                bf16x8 pa1 = *(const bf16x8*)&pwh[qt][0];
                accO[qt][ctd] = __builtin_amdgcn_mfma_f32_16x16x32_bf16(pa0, vf0, accO[qt][ctd], 0, 0, 0);
                accO[qt][ctd] = __builtin_amdgcn_mfma_f32_16x16x32_bf16(pa1, vf1, accO[qt][ctd], 0, 0, 0);
            }
        }
        __builtin_amdgcn_s_setprio(0);
    }
#undef STAGE

    // epilogue: direct write
#pragma unroll
    for (int qt = 0; qt < 2; ++qt)
#pragma unroll
        for (int r = 0; r < 4; ++r) {
            float inv = 1.0f / accL[qt][r];
            int q = q0 + qt * 16 + g * 4 + r;
            bf16_t* orow = AO + ((size_t)(n * SEQ + q)) * EMBED + h * HDIM;
#pragma unroll
            for (int ctd = 0; ctd < 4; ++ctd)
                orow[ctd * 16 + lr] = (bf16_t)(accO[qt][ctd][r] * inv);
        }
}

// ------- Output projection: 128x128 tiles, DMA-staged bf16 A/B, XCD-local mapping -----
__global__ __launch_bounds__(256, 2) void outproj_kernel(const bf16_t* __restrict__ Xa,
                                                         const bf16_t* __restrict__ Wob,
                                                         const float* __restrict__ bo,
                                                         float* __restrict__ Out) {
    __shared__ __align__(16) bf16_t As[2][128 * 64];   // 16KB x2
    __shared__ __align__(16) bf16_t Bs[2][128 * 64];   // 16KB x2
    const int tid = threadIdx.x;
    const int lane = tid & 63, w = tid >> 6;
    const int lr = lane & 15, g = lane >> 4;
    const int wm = w >> 1, wn = w & 1;
    // XCD-local map: same-Xa-row blocks land on the same XCD (bid%8)
    const int bm = blockIdx.x & 63;   // 64 row-blocks
    const int bn = blockIdx.x >> 6;   // 8 col-blocks
    const int r0 = bm * 128, c0 = bn * 128;

    int srow[4], scx[4];
#pragma unroll
    for (int p = 0; p < 4; ++p) {
        srow[p] = p * 32 + w * 8 + (lane >> 3);
        scx[p] = (lane & 7) ^ (srow[p] & 7);    // pre-swizzled source chunk
    }

#define STG(s, b) { _Pragma("unroll") for (int p = 0; p < 4; ++p) { \
    gload_lds16(Xa  + (size_t)(r0 + srow[p]) * EMBED + (s) * 64 + scx[p] * 8, &As[b][0] + (p * 256 + w * 64) * 8); \
    gload_lds16(Wob + (size_t)(c0 + srow[p]) * EMBED + (s) * 64 + scx[p] * 8, &Bs[b][0] + (p * 256 + w * 64) * 8); } }

    f32x4 acc[4][4] = {};

    STG(0, 0);

    for (int ks = 0; ks < 16; ++ks) {
        const int cur = ks & 1;
        asm volatile("s_waitcnt vmcnt(0)" ::: "memory");
        __builtin_amdgcn_s_barrier();
        __builtin_amdgcn_sched_barrier(0);
        if (ks + 1 < 16) STG(ks + 1, cur ^ 1);

        const bf16_t* Ab = As[cur];
        const bf16_t* Bb = Bs[cur];
#pragma unroll
        for (int hf = 0; hf < 2; ++hf) {
            bf16x8 af[4], bfr[4];
#pragma unroll
            for (int i = 0; i < 4; ++i) {
                int ar = wm * 64 + i * 16 + lr;
                af[i] = *(const bf16x8*)(Ab + ar * 64 + (((hf * 4 + g) ^ (ar & 7)) << 3));
                int br = wn * 64 + i * 16 + lr;
                bfr[i] = *(const bf16x8*)(Bb + br * 64 + (((hf * 4 + g) ^ (br & 7)) << 3));
            }
            __builtin_amdgcn_s_setprio(1);
#pragma unroll
            for (int i = 0; i < 4; ++i)
#pragma unroll
                for (int j = 0; j < 4; ++j)
                    acc[i][j] = __builtin_amdgcn_mfma_f32_16x16x32_bf16(af[i], bfr[j], acc[i][j], 0, 0, 0);
            __builtin_amdgcn_s_setprio(0);
        }
    }
#undef STG

#pragma unroll
    for (int i = 0; i < 4; ++i)
#pragma unroll
        for (int r = 0; r < 4; ++r) {
            int row = r0 + wm * 64 + i * 16 + g * 4 + r;
            float* orow = Out + (size_t)row * EMBED;
#pragma unroll
            for (int j = 0; j < 4; ++j) {
                int col = c0 + wn * 64 + j * 16 + lr;
                orow[col] = acc[i][j][r] + bo[col];
            }
        }
}

extern "C" void kernel_launch(void* const* d_in, const int* in_sizes, int n_in,
                              void* d_out, int out_size, void* d_ws, size_t ws_size,
                              hipStream_t stream) {
    const float* values = (const float*)d_in[0];
    const float* keys   = (const float*)d_in[1];
    const float* query  = (const float*)d_in[2];
    const int*   mask   = (const int*)d_in[3];
    const float* Wv = (const float*)d_in[4];
    const float* Wk = (const float*)d_in[5];
    const float* Wq = (const float*)d_in[6];
    const float* Wo = (const float*)d_in[7];
    const float* bo = (const float*)d_in[8];
    float* out = (float*)d_out;

    char* ws = (char*)d_ws;
    const size_t SZ = (size_t)NB * HEADS * SEQ * HDIM * sizeof(bf16_t);  // 16 MB
    bf16_t* Qp  = (bf16_t*)(ws);
    bf16_t* Kp  = (bf16_t*)(ws + SZ);
    bf16_t* Vt  = (bf16_t*)(ws + 2 * SZ);
    bf16_t* Xa  = (bf16_t*)(ws + 3 * SZ);
    bf16_t* Wob = (bf16_t*)(ws + 4 * SZ);   // 2 MB

    const float qscale = 0.0450842200278f;  // log2(e) / sqrt(1024)

    dim3 blk(256);
    dim3 gproj(512, 4);   // y=0..2: Q/K/V projection; y=3: Wo->bf16 convert
    qkvproj_kernel<<<gproj, blk, 0, stream>>>(query, keys, values, Wq, Wk, Wv, Wo,
                                              Qp, Kp, Vt, Wob, qscale);

    const int attn_grid = 64 * (SEQ / QPB);   // 1024
    attn_kernel<<<dim3(attn_grid), blk, 0, stream>>>(Qp, Kp, Vt, mask, Xa);

    outproj_kernel<<<dim3(512), blk, 0, stream>>>(Xa, Wob, bo, out);
}

// Round 15
// 129.833 us; speedup vs baseline: 1.6315x; 1.0870x over previous
//
#include <hip/hip_runtime.h>
#include <hip/hip_bf16.h>

#define EMBED 1024
#define HEADS 16
#define HDIM 64
#define NB 4
#define SEQ 2048

typedef __bf16 bf16_t;
typedef bf16_t bf16x4 __attribute__((ext_vector_type(4)));
typedef bf16_t bf16x8 __attribute__((ext_vector_type(8)));
typedef float f32x4 __attribute__((ext_vector_type(4)));
typedef unsigned char u8;

static __device__ __forceinline__ bf16x8 cvt8(f32x4 a, f32x4 b) {
    bf16x8 r;
    r[0]=(bf16_t)a[0]; r[1]=(bf16_t)a[1]; r[2]=(bf16_t)a[2]; r[3]=(bf16_t)a[3];
    r[4]=(bf16_t)b[0]; r[5]=(bf16_t)b[1]; r[6]=(bf16_t)b[2]; r[7]=(bf16_t)b[3];
    return r;
}
static __device__ __forceinline__ bf16x8 load_cvt8(const float* __restrict__ p) {
    f32x4 a = *reinterpret_cast<const f32x4*>(p);
    f32x4 b = *reinterpret_cast<const f32x4*>(p + 4);
    return cvt8(a, b);
}
static __device__ __forceinline__ void gload_lds16(const bf16_t* g, bf16_t* l) {
    __builtin_amdgcn_global_load_lds((const __attribute__((address_space(1))) void*)g,
                                     (__attribute__((address_space(3))) void*)l, 16, 0, 0);
}
static __device__ __forceinline__ void gload_lds16u(const u8* g, u8* l) {
    __builtin_amdgcn_global_load_lds((const __attribute__((address_space(1))) void*)g,
                                     (__attribute__((address_space(3))) void*)l, 16, 0, 0);
}
// pack 4 f32 -> 4 fp8 e4m3 in one dword
static __device__ __forceinline__ unsigned int pk_fp8x4(float z0, float z1, float z2, float z3) {
    unsigned int ww = __builtin_amdgcn_cvt_pk_fp8_f32(z0, z1, 0, false);
    ww = __builtin_amdgcn_cvt_pk_fp8_f32(z2, z3, ww, true);
    return ww;
}

// ------- Fused QKV projection (Q,K fp8; V bf16) + Wo convert (mode 3) -------
__global__ __launch_bounds__(256) void qkvproj_kernel(const float* __restrict__ Xq,
                                                      const float* __restrict__ Xk,
                                                      const float* __restrict__ Xv,
                                                      const float* __restrict__ Wq,
                                                      const float* __restrict__ Wk,
                                                      const float* __restrict__ Wv,
                                                      const float* __restrict__ Wo,
                                                      u8* __restrict__ Qo,
                                                      u8* __restrict__ Ko,
                                                      bf16_t* __restrict__ Vo,
                                                      bf16_t* __restrict__ Wob) {
    const int mode = blockIdx.y;
    if (mode == 3) {   // Wo -> bf16
        const size_t i = ((size_t)blockIdx.x * 256 + threadIdx.x) * 8;
        f32x4 a = *reinterpret_cast<const f32x4*>(Wo + i);
        f32x4 b = *reinterpret_cast<const f32x4*>(Wo + i + 4);
        *(bf16x8*)(Wob + i) = cvt8(a, b);
        return;
    }
    const float* X = (mode == 0) ? Xq : (mode == 1) ? Xk : Xv;
    const float* W = (mode == 0) ? Wq : (mode == 1) ? Wk : Wv;
    const int lane = threadIdx.x & 63, w = threadIdx.x >> 6;
    const int lr = lane & 15, g = lane >> 4;
    const int nh = blockIdx.x >> 3;    // 64
    const int scb = blockIdx.x & 7;    // 8 super-chunks of 256 s
    const int n = nh >> 4, h = nh & 15;

    bf16x8 wA[4][2];
#pragma unroll
    for (int dt = 0; dt < 4; ++dt) {
        const float* wrow = W + (size_t)(dt * 16 + lr) * HDIM;
        wA[dt][0] = load_cvt8(wrow + g * 8);
        wA[dt][1] = load_cvt8(wrow + 32 + g * 8);
    }

#pragma unroll
    for (int it = 0; it < 4; ++it) {
        const int s0 = scb * 256 + it * 64 + w * 16;
        const float* xrow = X + ((size_t)n * SEQ + s0 + lr) * EMBED + h * HDIM;
        bf16x8 x0 = load_cvt8(xrow + g * 8);
        bf16x8 x1 = load_cvt8(xrow + 32 + g * 8);

        f32x4 acc[4] = {};
#pragma unroll
        for (int dt = 0; dt < 4; ++dt) {
            if (mode == 2) {
                acc[dt] = __builtin_amdgcn_mfma_f32_16x16x32_bf16(x0, wA[dt][0], acc[dt], 0, 0, 0);
                acc[dt] = __builtin_amdgcn_mfma_f32_16x16x32_bf16(x1, wA[dt][1], acc[dt], 0, 0, 0);
            } else {
                acc[dt] = __builtin_amdgcn_mfma_f32_16x16x32_bf16(wA[dt][0], x0, acc[dt], 0, 0, 0);
                acc[dt] = __builtin_amdgcn_mfma_f32_16x16x32_bf16(wA[dt][1], x1, acc[dt], 0, 0, 0);
            }
        }
        if (mode == 2) {
            // V^T bf16, key-permuted (R13 path)
            const int sc4 = scb * 4 + it;
#pragma unroll
            for (int et = 0; et < 4; ++et) {
                bf16x4 o;
#pragma unroll
                for (int r = 0; r < 4; ++r) o[r] = (bf16_t)acc[et][r];
                *(bf16x4*)(Vo + ((size_t)nh * HDIM + et * 16 + lr) * SEQ
                              + sc4 * 64 + ((w >> 1) << 5) + (g << 3) + ((w & 1) << 2)) = o;
            }
        } else {
            // Q/K fp8 e4m3, natural scale (R14 path)
            u8* Yo = (mode == 0) ? Qo : Ko;
#pragma unroll
            for (int dt = 0; dt < 4; ++dt) {
                unsigned int ww = pk_fp8x4(acc[dt][0], acc[dt][1], acc[dt][2], acc[dt][3]);
                *(unsigned int*)(Yo + ((size_t)nh * SEQ + s0 + lr) * HDIM + dt * 16 + (g << 2)) = ww;
            }
        }
    }
}

// ------- Flash attention: fp8 QK^T + bf16 PV, 4-wave blocks, QPW=32, dbuf DMA staging --
#define KT 64
#define QPW 32
#define QPB 128
#define NT (SEQ / KT)   // 32
// swizzled byte offset for 8B chunk cc of a 64B fp8 row (granule swizzle gr ^= (row>>1)&3)
#define KOFF(row, cc) ((row) * 64 + (((((cc) >> 1) ^ (((row) >> 1) & 3)) << 4) | (((cc) & 1) << 3)))

__global__ __launch_bounds__(256, 4) void attn_kernel(const u8* __restrict__ Qp,
                                                      const u8* __restrict__ Kp,
                                                      const bf16_t* __restrict__ Vt_g,
                                                      const int* __restrict__ mask,
                                                      bf16_t* __restrict__ AO) {
    __shared__ __align__(16) u8 Kt[2][4096];          // 8KB  (fp8 K tiles)
    __shared__ __align__(16) bf16_t Vt[2][64 * 64];   // 16KB (bf16 V^T tiles)

    const int tid = threadIdx.x;
    const int lane = tid & 63;
    const int w = tid >> 6;          // 0..3
    const int lr = lane & 15, g = lane >> 4;

    const int nh = blockIdx.x & 63;  // XCD locality
    const int qb = blockIdx.x >> 6;  // 0..15
    const int n = nh >> 4, h = nh & 15;

    const u8* Qh = Qp + (size_t)nh * SEQ * HDIM;
    const u8* Kh = Kp + (size_t)nh * SEQ * HDIM;
    const bf16_t* Vh = Vt_g + (size_t)nh * HDIM * SEQ;   // [d][s_perm]
    const int* mrow = mask + n * SEQ;

    const float qscale = 0.0450842200278f;  // log2(e) / sqrt(1024)

    const int q0 = qb * QPB + w * QPW;
    long Qreg[2][2];
#pragma unroll
    for (int qt = 0; qt < 2; ++qt)
#pragma unroll
        for (int kh = 0; kh < 2; ++kh)
            Qreg[qt][kh] = *(const long*)(Qh + (size_t)(q0 + qt * 16 + lr) * HDIM + kh * 32 + g * 8);

    // pack mask into one bit per tile
    unsigned int mbits = 0;
    for (int t = 0; t < NT; ++t)
        mbits |= (mrow[t * 64 + lane] != 0 ? 1u : 0u) << t;

    // K staging: 256 threads x 16B granules, pre-swizzled source (R14, verified)
    const int grow = tid >> 2;                        // row 0..63
    const int glog = (tid & 3) ^ ((grow >> 1) & 3);   // source granule
    // V staging: thread covers rows srow, srow+32 (R13, verified)
    const int srow = (w << 3) + (lane >> 3);          // 0..31
    const int sx = (lane & 7) ^ (srow & 7);           // pre-swizzled chunk

#define STAGE(t, b) { \
    gload_lds16u(Kh + ((size_t)((t) * 64 + grow)) * 64 + glog * 16, &Kt[b][0] + tid * 16); \
    gload_lds16(Vh + (size_t)srow * SEQ + (t) * 64 + sx * 8,        &Vt[b][0]    + w * 512); \
    gload_lds16(Vh + (size_t)(srow + 32) * SEQ + (t) * 64 + sx * 8, &Vt[b][2048] + w * 512); }

    f32x4 accO[2][4] = {};
    f32x4 accL[2] = {};
    bf16x8 ones;
#pragma unroll
    for (int j = 0; j < 8; ++j) ones[j] = (bf16_t)1.0f;

    STAGE(0, 0);

    for (int t = 0; t < NT; ++t) {
        const int cur = t & 1;
        asm volatile("s_waitcnt vmcnt(0)" ::: "memory");
        __builtin_amdgcn_s_barrier();
        __builtin_amdgcn_sched_barrier(0);
        if (t + 1 < NT) STAGE(t + 1, cur ^ 1);

        const u8* Kb = &Kt[cur][0];
        const bf16_t* Vb = &Vt[cur][0];

        const int mbit = (int)((mbits >> t) & 1u);
        const bool allone = __all(mbit);

        // QK^T in fp8 (A=K rows, B=Q), post-MFMA scale+exp2; P packed bf16 via cvt_pk
        unsigned int pwl[2][4], pwh[2][4];
#pragma unroll
        for (int ct = 0; ct < 4; ++ct) {
            int row = ct * 16 + lr;
            long kf0 = *(const long*)(Kb + KOFF(row, g));
            long kf1 = *(const long*)(Kb + KOFF(row, 4 + g));
#pragma unroll
            for (int qt = 0; qt < 2; ++qt) {
                f32x4 z = {};
                z = __builtin_amdgcn_mfma_f32_16x16x32_fp8_fp8(kf0, Qreg[qt][0], z, 0, 0, 0);
                z = __builtin_amdgcn_mfma_f32_16x16x32_fp8_fp8(kf1, Qreg[qt][1], z, 0, 0, 0);
                if (allone) {
#pragma unroll
                    for (int r = 0; r < 4; ++r) z[r] = __builtin_amdgcn_exp2f(z[r] * qscale);
                } else {
#pragma unroll
                    for (int r = 0; r < 4; ++r) {
                        int key = ct * 16 + g * 4 + r;
                        int mk = __shfl(mbit, key);
                        z[r] = mk ? __builtin_amdgcn_exp2f(z[r] * qscale) : 0.f;
                    }
                }
                unsigned int w0, w1;
                asm("v_cvt_pk_bf16_f32 %0, %1, %2" : "=v"(w0) : "v"(z[0]), "v"(z[1]));
                asm("v_cvt_pk_bf16_f32 %0, %1, %2" : "=v"(w1) : "v"(z[2]), "v"(z[3]));
                if (ct == 0)      { pwl[qt][0] = w0; pwl[qt][1] = w1; }
                else if (ct == 1) { pwl[qt][2] = w0; pwl[qt][3] = w1; }
                else if (ct == 2) { pwh[qt][0] = w0; pwh[qt][1] = w1; }
                else              { pwh[qt][2] = w0; pwh[qt][3] = w1; }
            }
        }

        // PV + denominator in bf16 (ones-column MFMA; key-perm invariant)
        __builtin_amdgcn_s_setprio(1);
#pragma unroll
        for (int qt = 0; qt < 2; ++qt) {
            bf16x8 pa0 = *(const bf16x8*)&pwl[qt][0];
            bf16x8 pa1 = *(const bf16x8*)&pwh[qt][0];
            accL[qt] = __builtin_amdgcn_mfma_f32_16x16x32_bf16(pa0, ones, accL[qt], 0, 0, 0);
            accL[qt] = __builtin_amdgcn_mfma_f32_16x16x32_bf16(pa1, ones, accL[qt], 0, 0, 0);
        }
#pragma unroll
        for (int ctd = 0; ctd < 4; ++ctd) {
            int row = ctd * 16 + lr, rs = row & 7;
            bf16x8 vf0 = *(const bf16x8*)(Vb + row * 64 + ((g ^ rs) << 3));
            bf16x8 vf1 = *(const bf16x8*)(Vb + row * 64 + (((4 + g) ^ rs) << 3));
#pragma unroll
            for (int qt = 0; qt < 2; ++qt) {
                bf16x8 pa0 = *(const bf16x8*)&pwl[qt][0];
                bf16x8 pa1 = *(const bf16x8*)&pwh[qt][0];
                accO[qt][ctd] = __builtin_amdgcn_mfma_f32_16x16x32_bf16(pa0, vf0, accO[qt][ctd], 0, 0, 0);
                accO[qt][ctd] = __builtin_amdgcn_mfma_f32_16x16x32_bf16(pa1, vf1, accO[qt][ctd], 0, 0, 0);
            }
        }
        __builtin_amdgcn_s_setprio(0);
    }
#undef STAGE

    // epilogue: direct write
#pragma unroll
    for (int qt = 0; qt < 2; ++qt)
#pragma unroll
        for (int r = 0; r < 4; ++r) {
            float inv = 1.0f / accL[qt][r];
            int q = q0 + qt * 16 + g * 4 + r;
            bf16_t* orow = AO + ((size_t)(n * SEQ + q)) * EMBED + h * HDIM;
#pragma unroll
            for (int ctd = 0; ctd < 4; ++ctd)
                orow[ctd * 16 + lr] = (bf16_t)(accO[qt][ctd][r] * inv);
        }
}

// ------- Output projection: 128x128 tiles, DMA-staged bf16 A/B, XCD-local mapping -----
__global__ __launch_bounds__(256, 2) void outproj_kernel(const bf16_t* __restrict__ Xa,
                                                         const bf16_t* __restrict__ Wob,
                                                         const float* __restrict__ bo,
                                                         float* __restrict__ Out) {
    __shared__ __align__(16) bf16_t As[2][128 * 64];
    __shared__ __align__(16) bf16_t Bs[2][128 * 64];
    const int tid = threadIdx.x;
    const int lane = tid & 63, w = tid >> 6;
    const int lr = lane & 15, g = lane >> 4;
    const int wm = w >> 1, wn = w & 1;
    const int bm = blockIdx.x & 63;
    const int bn = blockIdx.x >> 6;
    const int r0 = bm * 128, c0 = bn * 128;

    int srow[4], scx[4];
#pragma unroll
    for (int p = 0; p < 4; ++p) {
        srow[p] = p * 32 + w * 8 + (lane >> 3);
        scx[p] = (lane & 7) ^ (srow[p] & 7);
    }

#define STG(s, b) { _Pragma("unroll") for (int p = 0; p < 4; ++p) { \
    gload_lds16(Xa  + (size_t)(r0 + srow[p]) * EMBED + (s) * 64 + scx[p] * 8, &As[b][0] + (p * 256 + w * 64) * 8); \
    gload_lds16(Wob + (size_t)(c0 + srow[p]) * EMBED + (s) * 64 + scx[p] * 8, &Bs[b][0] + (p * 256 + w * 64) * 8); } }

    f32x4 acc[4][4] = {};

    STG(0, 0);

    for (int ks = 0; ks < 16; ++ks) {
        const int cur = ks & 1;
        asm volatile("s_waitcnt vmcnt(0)" ::: "memory");
        __builtin_amdgcn_s_barrier();
        __builtin_amdgcn_sched_barrier(0);
        if (ks + 1 < 16) STG(ks + 1, cur ^ 1);

        const bf16_t* Ab = As[cur];
        const bf16_t* Bb = Bs[cur];
#pragma unroll
        for (int hf = 0; hf < 2; ++hf) {
            bf16x8 af[4], bfr[4];
#pragma unroll
            for (int i = 0; i < 4; ++i) {
                int ar = wm * 64 + i * 16 + lr;
                af[i] = *(const bf16x8*)(Ab + ar * 64 + (((hf * 4 + g) ^ (ar & 7)) << 3));
                int br = wn * 64 + i * 16 + lr;
                bfr[i] = *(const bf16x8*)(Bb + br * 64 + (((hf * 4 + g) ^ (br & 7)) << 3));
            }
            __builtin_amdgcn_s_setprio(1);
#pragma unroll
            for (int i = 0; i < 4; ++i)
#pragma unroll
                for (int j = 0; j < 4; ++j)
                    acc[i][j] = __builtin_amdgcn_mfma_f32_16x16x32_bf16(af[i], bfr[j], acc[i][j], 0, 0, 0);
            __builtin_amdgcn_s_setprio(0);
        }
    }
#undef STG

#pragma unroll
    for (int i = 0; i < 4; ++i)
#pragma unroll
        for (int r = 0; r < 4; ++r) {
            int row = r0 + wm * 64 + i * 16 + g * 4 + r;
            float* orow = Out + (size_t)row * EMBED;
#pragma unroll
            for (int j = 0; j < 4; ++j) {
                int col = c0 + wn * 64 + j * 16 + lr;
                orow[col] = acc[i][j][r] + bo[col];
            }
        }
}

extern "C" void kernel_launch(void* const* d_in, const int* in_sizes, int n_in,
                              void* d_out, int out_size, void* d_ws, size_t ws_size,
                              hipStream_t stream) {
    const float* values = (const float*)d_in[0];
    const float* keys   = (const float*)d_in[1];
    const float* query  = (const float*)d_in[2];
    const int*   mask   = (const int*)d_in[3];
    const float* Wv = (const float*)d_in[4];
    const float* Wk = (const float*)d_in[5];
    const float* Wq = (const float*)d_in[6];
    const float* Wo = (const float*)d_in[7];
    const float* bo = (const float*)d_in[8];
    float* out = (float*)d_out;

    char* ws = (char*)d_ws;
    const size_t SZ8  = (size_t)NB * HEADS * SEQ * HDIM;                 // 8 MB (fp8)
    const size_t SZBF = SZ8 * sizeof(bf16_t);                            // 16 MB (bf16)
    u8* Qp      = (u8*)(ws);
    u8* Kp      = (u8*)(ws + SZ8);
    bf16_t* Vt  = (bf16_t*)(ws + 2 * SZ8);                               // 16 MB
    bf16_t* Xa  = (bf16_t*)(ws + 2 * SZ8 + SZBF);                        // 16 MB
    bf16_t* Wob = (bf16_t*)(ws + 2 * SZ8 + 2 * SZBF);                    // 2 MB

    dim3 blk(256);
    dim3 gproj(512, 4);   // y=0: Q(fp8)  y=1: K(fp8)  y=2: V^T(bf16)  y=3: Wo cvt
    qkvproj_kernel<<<gproj, blk, 0, stream>>>(query, keys, values, Wq, Wk, Wv, Wo,
                                              Qp, Kp, Vt, Wob);

    const int attn_grid = 64 * (SEQ / QPB);   // 1024
    attn_kernel<<<dim3(attn_grid), blk, 0, stream>>>(Qp, Kp, Vt, mask, Xa);

    outproj_kernel<<<dim3(512), blk, 0, stream>>>(Xa, Wob, bo, out);
}